// Round 1
// baseline (302.208 us; speedup 1.0000x reference)
//
#include <hip/hip_runtime.h>
#include <stdint.h>

// Problem constants (from reference):
constexpr int kB   = 8;
constexpr int kL1  = 1024;
constexpr int kC   = 128;
constexpr int kL2  = 256;
constexpr int kS   = 16;
constexpr int kNQ  = kB * kS;        // 128 queries
constexpr int kNDB = 8192;
constexpr float kEPS = 1e-8f;
constexpr int kRow = kC * kL2;       // 32768 floats per database row

// ---------------------------------------------------------------------------
// Phase 0: build the gather-address table.
// For query q = b*16+s and position l2:
//   start = kp[b][s]; end = max(kp[b][s+1], start+1)
//   pos = f32(start) + f32(end-start) * ((l2+0.5)/256)   (mul then add, NO fma,
//         to match jnp's two separately-rounded f32 ops)
//   idx = clip(trunc(pos), 0, 1023); c = seq[b][idx]
// Packed LDS address for the main kernel: (l2 & 63)*129 + c  (fits uint16).
// ---------------------------------------------------------------------------
__global__ void build_addr_kernel(const int* __restrict__ seq,
                                  const int* __restrict__ kp,
                                  uint16_t* __restrict__ addr16) {
    const int q  = blockIdx.x;    // 0..127
    const int l2 = threadIdx.x;   // 0..255
    const int b = q >> 4;
    const int s = q & 15;
    int start = kp[b * (kS + 1) + s];
    int end_  = kp[b * (kS + 1) + s + 1];
    if (end_ < start + 1) end_ = start + 1;
    const float frac = (l2 + 0.5f) * (1.0f / 256.0f);   // exact (pow2 divide)
    const float pos = __fadd_rn((float)start, __fmul_rn((float)(end_ - start), frac));
    int idx = (int)pos;                                  // trunc, pos >= 0
    idx = idx < 0 ? 0 : (idx > kL1 - 1 ? kL1 - 1 : idx);
    const int c = seq[b * kL1 + idx];
    addr16[q * kL2 + l2] = (uint16_t)((l2 & 63) * 129 + c);
}

// ---------------------------------------------------------------------------
// Phase 1: one block per database row n.
//   - Stream the 128 KiB row in 4 chunks of (128 c x 64 l2), float4-coalesced.
//   - Fuse ||d_n||^2 into the staging loads.
//   - LDS tile transposed+padded: tile[l2l*129 + c].
//       * writes: lanes hit 32 banks x 2 -> conflict-free
//       * gather reads: bank = (l2l + c) % 32 with random c -> well spread
//   - Thread t owns query q = t&127, half h = t>>7 (32 l2 per chunk each).
//   - Block-reduce norm, scale, write sims[q*8192 + n].
// ---------------------------------------------------------------------------
__launch_bounds__(256, 4)
__global__ void sim_kernel(const float* __restrict__ db,
                           const uint16_t* __restrict__ addr16,
                           float* __restrict__ sims) {
    __shared__ float tile[64 * 129];   // 33,024 B
    __shared__ float accbuf[256];
    __shared__ float nbuf[256];

    const int n = blockIdx.x;
    const int t = threadIdx.x;
    const int q = t & 127;
    const int h = t >> 7;
    const float* rowp = db + (size_t)n * kRow;

    float a0 = 0.f, a1 = 0.f, a2 = 0.f, a3 = 0.f;
    float nrm = 0.f;

    for (int chunk = 0; chunk < 4; ++chunk) {
        // ---- stage chunk into LDS (transposed) + norm accumulation ----
        #pragma unroll
        for (int k = 0; k < 8; ++k) {
            const int j   = (t + 256 * k) * 4;   // flat float index in chunk
            const int c   = j >> 6;              // 0..127
            const int l2l = j & 63;              // multiple of 4
            const float4 v = *reinterpret_cast<const float4*>(
                rowp + c * 256 + chunk * 64 + l2l);
            nrm = fmaf(v.x, v.x, nrm);
            nrm = fmaf(v.y, v.y, nrm);
            nrm = fmaf(v.z, v.z, nrm);
            nrm = fmaf(v.w, v.w, nrm);
            tile[(l2l + 0) * 129 + c] = v.x;
            tile[(l2l + 1) * 129 + c] = v.y;
            tile[(l2l + 2) * 129 + c] = v.z;
            tile[(l2l + 3) * 129 + c] = v.w;
        }
        __syncthreads();

        // ---- gather: 32 elements for (q, h) from precomputed addresses ----
        const uint16_t* ap = addr16 + q * kL2 + chunk * 64 + h * 32;
        #pragma unroll
        for (int g = 0; g < 4; ++g) {
            union { uint4 v; uint16_t u[8]; } pk;
            pk.v = *reinterpret_cast<const uint4*>(ap + g * 8);
            a0 += tile[pk.u[0]];
            a1 += tile[pk.u[1]];
            a2 += tile[pk.u[2]];
            a3 += tile[pk.u[3]];
            a0 += tile[pk.u[4]];
            a1 += tile[pk.u[5]];
            a2 += tile[pk.u[6]];
            a3 += tile[pk.u[7]];
        }
        __syncthreads();
    }

    accbuf[t] = (a0 + a1) + (a2 + a3);
    nbuf[t]   = nrm;
    __syncthreads();
    for (int s2 = 128; s2 > 0; s2 >>= 1) {
        if (t < s2) nbuf[t] += nbuf[t + s2];
        __syncthreads();
    }
    if (t < 128) {
        const float total = accbuf[t] + accbuf[t + 128];
        const float norm  = sqrtf(nbuf[0]);
        const float inv   = 1.0f / ((norm + kEPS) * (16.0f + kEPS));
        sims[(size_t)t * kNDB + n] = total * inv;
    }
}

// ---------------------------------------------------------------------------
// Phase 2: per-query argmax over 8192 (first-max tie-break = lowest index),
// predictions = float(db_classes[argmax]), unit_sim = max.
// ---------------------------------------------------------------------------
__global__ void argmax_kernel(const float* __restrict__ sims,
                              const int* __restrict__ db_classes,
                              float* __restrict__ preds,
                              float* __restrict__ unit) {
    const int q = blockIdx.x;
    const int t = threadIdx.x;
    const float* row = sims + (size_t)q * kNDB;

    float best = -1e30f;
    int bidx = kNDB;
    for (int n = t; n < kNDB; n += 256) {   // increasing n: '>' keeps first max
        const float v = row[n];
        if (v > best) { best = v; bidx = n; }
    }

    __shared__ float bv[256];
    __shared__ int   bi[256];
    bv[t] = best;
    bi[t] = bidx;
    __syncthreads();
    for (int s2 = 128; s2 > 0; s2 >>= 1) {
        if (t < s2) {
            const float ov = bv[t + s2];
            const int   oi = bi[t + s2];
            if (ov > bv[t] || (ov == bv[t] && oi < bi[t])) {
                bv[t] = ov;
                bi[t] = oi;
            }
        }
        __syncthreads();
    }
    if (t == 0) {
        preds[q] = (float)db_classes[bi[0]];
        unit[q]  = bv[0];
    }
}

// ---------------------------------------------------------------------------
extern "C" void kernel_launch(void* const* d_in, const int* in_sizes, int n_in,
                              void* d_out, int out_size, void* d_ws, size_t ws_size,
                              hipStream_t stream) {
    const int*   seq        = (const int*)d_in[0];     // (8, 1024) int32
    const int*   kp         = (const int*)d_in[1];     // (8, 17)   int32
    const float* db         = (const float*)d_in[2];   // (8192, 128, 256) f32
    const int*   db_classes = (const int*)d_in[3];     // (8192,)   int32

    float* out   = (float*)d_out;                 // sims | preds | unit_sim
    float* preds = out + (size_t)kNQ * kNDB;      // + 1048576
    float* unit  = preds + kNQ;                   // + 128

    uint16_t* addr16 = (uint16_t*)d_ws;           // 64 KiB scratch

    build_addr_kernel<<<kNQ, kL2, 0, stream>>>(seq, kp, addr16);
    sim_kernel<<<kNDB, 256, 0, stream>>>(db, addr16, out);
    argmax_kernel<<<kNQ, 256, 0, stream>>>(out, db_classes, preds, unit);
}